// Round 2
// baseline (11378.620 us; speedup 1.0000x reference)
//
#include <hip/hip_runtime.h>
#include <stdint.h>

// ---------------------------------------------------------------------------
// LSTM forward, T=2048 B=64 I=H=512.  Fully fused main kernel:
//   - 64 "rec" WGs (4 batch-groups x 16 hidden-groups): persistent recurrence,
//     W_h slice (128 cols x 512) stationary in LDS, split-N over 4 waves
//     (wave = gate), flag-based agent-scope sync within each batch-group.
//   - 192 "gemm" WGs: Xg = Xb @ Wx (bf16 MFMA, 128x128 tiles) produced
//     time-major, published via per-row-block progress counters.
// ---------------------------------------------------------------------------

typedef __attribute__((ext_vector_type(8))) short short8;
typedef __attribute__((ext_vector_type(4))) float f32x4;

#define T_STEPS 2048
#define GBN 4
#define GHN 16
#define NREC 64    // GBN*GHN rec workgroups
#define NWORK 192  // gemm worker workgroups
#define FSTRIDE 16 // ints between flags (64B line spacing)

__device__ __forceinline__ unsigned short f2bf(float f) {
  unsigned int x = __float_as_uint(f);
  x += 0x7fffu + ((x >> 16) & 1u);  // RNE
  return (unsigned short)(x >> 16);
}
__device__ __forceinline__ float bf2f(unsigned short u) {
  return __uint_as_float(((unsigned int)u) << 16);
}
__device__ __forceinline__ void gl2lds16(const void* g, void* lds) {
  __builtin_amdgcn_global_load_lds(
      (const __attribute__((address_space(1))) void*)(uintptr_t)g,
      (__attribute__((address_space(3))) void*)(unsigned int)(uintptr_t)lds,
      16, 0, 0);
}

union Smem {
  struct { unsigned short As[128 * 64]; unsigned short Bs[128 * 64]; } g;
  struct { unsigned short Wl[128][520]; float Cg[4][16][33]; } r;
};

// --------------------------- pre-phase kernels ------------------------------

__global__ __launch_bounds__(256) void cast_x_kernel(
    const float* __restrict__ X, unsigned short* __restrict__ Xb) {
  long long i = ((long long)blockIdx.x * 256 + threadIdx.x) * 8;
  float4 a = *(const float4*)(X + i);
  float4 b = *(const float4*)(X + i + 4);
  union { short8 v; unsigned short u[8]; } o;
  o.u[0] = f2bf(a.x); o.u[1] = f2bf(a.y); o.u[2] = f2bf(a.z); o.u[3] = f2bf(a.w);
  o.u[4] = f2bf(b.x); o.u[5] = f2bf(b.y); o.u[6] = f2bf(b.z); o.u[7] = f2bf(b.w);
  *(short8*)(Xb + i) = o.v;
}

// Wt[n][k] = W_gate(n/512)[k][n%512]  (transposed, bf16), n in [0,2048)
__global__ __launch_bounds__(256) void pack_w_kernel(
    const float* __restrict__ Wf, const float* __restrict__ Wi,
    const float* __restrict__ Wo, const float* __restrict__ Wc,
    unsigned short* __restrict__ Wt) {
  int n = blockIdx.x;
  int g = n >> 9, h = n & 511;
  const float* W = (g == 0) ? Wf : (g == 1) ? Wi : (g == 2) ? Wo : Wc;
  for (int k = threadIdx.x; k < 512; k += 256)
    Wt[(size_t)n * 512 + k] = f2bf(W[(size_t)k * 512 + h]);
}

__global__ __launch_bounds__(256) void init_kernel(unsigned short* hbuf,
                                                   int* flags, int* xgprog) {
  int i = blockIdx.x * 256 + threadIdx.x;
  if (i < 2 * 64 * 512) hbuf[i] = 0;
  if (i < NREC * FSTRIDE) flags[i] = 0;
  if (i < 1024) xgprog[i] = 0;
}

// ------------------------------ fused kernel --------------------------------

__global__ __launch_bounds__(256, 1) void lstm_fused_kernel(
    const unsigned short* __restrict__ Xb,   // [131072][512] bf16
    const unsigned short* __restrict__ Wxt,  // [2048][512] bf16 (transposed)
    const unsigned short* __restrict__ Wht,  // [2048][512] bf16 (transposed)
    unsigned short* __restrict__ Xg,         // [131072][2048] bf16 (ws)
    const float* __restrict__ b_f, const float* __restrict__ b_i,
    const float* __restrict__ b_o, const float* __restrict__ b_c,
    float* __restrict__ out, unsigned short* hbuf, int* flags, int* xgprog) {
  __shared__ Smem sm;
  const int tid = threadIdx.x;
  const int lane = tid & 63, wave = tid >> 6;
  const int wg = blockIdx.x;

  if (wg >= NREC) {
    // ------------------------- GEMM worker path ----------------------------
    const int q = wg - NREC;
    const int wm = (wave & 1) * 64, wn = (wave >> 1) * 64;
    for (int tau = q; tau < 16384; tau += NWORK) {
      const int mt = tau >> 4, nt = tau & 15;
      f32x4 acc[4][4];
#pragma unroll
      for (int i = 0; i < 4; ++i)
#pragma unroll
        for (int j = 0; j < 4; ++j) acc[i][j] = (f32x4){0.f, 0.f, 0.f, 0.f};

      for (int kt = 0; kt < 512; kt += 64) {
        __syncthreads();  // LDS safe to overwrite
#pragma unroll
        for (int r = 0; r < 4; ++r) {
          int chunk = r * 256 + tid;  // row=chunk>>3, c8=chunk&7
          int row = chunk >> 3, c8 = chunk & 7;
          gl2lds16(Xb + ((size_t)(mt * 128 + row) * 512 + kt + c8 * 8),
                   (void*)(sm.g.As + (size_t)(r * 256 + wave * 64) * 8));
          gl2lds16(Wxt + ((size_t)(nt * 128 + row) * 512 + kt + c8 * 8),
                   (void*)(sm.g.Bs + (size_t)(r * 256 + wave * 64) * 8));
        }
        __syncthreads();  // staging complete
#pragma unroll
        for (int kc = 0; kc < 64; kc += 32) {
          const int ko = kc + (lane >> 4) * 8;
          short8 av[4], bv[4];
#pragma unroll
          for (int mi = 0; mi < 4; ++mi)
            av[mi] = *(const short8*)(sm.g.As + (wm + mi * 16 + (lane & 15)) * 64 + ko);
#pragma unroll
          for (int ni = 0; ni < 4; ++ni)
            bv[ni] = *(const short8*)(sm.g.Bs + (wn + ni * 16 + (lane & 15)) * 64 + ko);
#pragma unroll
          for (int mi = 0; mi < 4; ++mi)
#pragma unroll
            for (int ni = 0; ni < 4; ++ni)
              acc[mi][ni] = __builtin_amdgcn_mfma_f32_16x16x32_bf16(
                  av[mi], bv[ni], acc[mi][ni], 0, 0, 0);
        }
      }
      // C write: agent-scope (sc1) stores -> L3, visible to rec WGs
      const int q4 = lane >> 4, cidx = lane & 15;
#pragma unroll
      for (int mi = 0; mi < 4; ++mi)
#pragma unroll
        for (int ni = 0; ni < 4; ++ni)
#pragma unroll
          for (int r = 0; r < 4; ++r) {
            int row = wm + mi * 16 + q4 * 4 + r;
            int col = wn + ni * 16 + cidx;
            __hip_atomic_store(
                Xg + (size_t)(mt * 128 + row) * 2048 + nt * 128 + col,
                f2bf(acc[mi][ni][r]), __ATOMIC_RELAXED, __HIP_MEMORY_SCOPE_AGENT);
          }
      __syncthreads();  // drains every wave's vmcnt -> all C stores landed
      if (tid == 0)
        __hip_atomic_fetch_add(xgprog + mt, 1, __ATOMIC_RELAXED,
                               __HIP_MEMORY_SCOPE_AGENT);
    }
    return;
  }

  // --------------------------- recurrence path -----------------------------
  const int gb = wg >> 4;   // batch group: rows gb*16..+16
  const int gh = wg & 15;   // hidden group: 32 hidden cols per gate
  const unsigned* Xgu = (const unsigned*)Xg;

  // Load W_h slice: 128 cols (4 gates x 32) x 512 k, transposed, padded LDS
  for (int idx = tid; idx < 128 * 64; idx += 256) {
    int cc = idx >> 6, k8 = idx & 63;
    int n = (cc >> 5) * 512 + gh * 32 + (cc & 31);
    short8 v = *(const short8*)(Wht + (size_t)n * 512 + k8 * 8);
    *(short8*)(&sm.r.Wl[cc][k8 * 8]) = v;
  }

  const int bb = tid >> 4, rem = tid & 15, jj2 = rem * 2;
  const float2 bfv = *(const float2*)(b_f + gh * 32 + jj2);
  const float2 biv = *(const float2*)(b_i + gh * 32 + jj2);
  const float2 bov = *(const float2*)(b_o + gh * 32 + jj2);
  const float2 bcv = *(const float2*)(b_c + gh * 32 + jj2);
  float c0 = 0.f, c1 = 0.f;

  const int m = lane & 15, quad = lane >> 4;
  const unsigned short* wl0 = &sm.r.Wl[wave * 32 + m][0];
  const unsigned short* wl1 = &sm.r.Wl[wave * 32 + 16 + m][0];
  const int myflag = wg * FSTRIDE;
  __syncthreads();

  for (int t = 0; t < T_STEPS; ++t) {
    // ---- spin: peer h flags (lanes 0..15) + Xg readiness (lane 16) ----
    if (wave == 0) {
      for (;;) {
        int ok = 1;
        if (lane < GHN) {
          int v = __hip_atomic_load(flags + (gb * GHN + lane) * FSTRIDE,
                                    __ATOMIC_RELAXED, __HIP_MEMORY_SCOPE_AGENT);
          ok = (v >= t);
        } else if (lane == GHN) {
          int p = __hip_atomic_load(xgprog + (t >> 1), __ATOMIC_RELAXED,
                                    __HIP_MEMORY_SCOPE_AGENT);
          ok = (p >= 16);
        }
        if (__all(ok)) break;
        __builtin_amdgcn_s_sleep(1);
      }
    }
    __syncthreads();
    __builtin_amdgcn_fence(__ATOMIC_ACQUIRE, "workgroup");

    // ---- Xg slice for this step (sc1 loads: producer wrote sc1) ----
    unsigned xgw[4];
    {
      size_t xrow = ((size_t)t * 64 + gb * 16 + bb) * 1024 + gh * 16 + rem;
#pragma unroll
      for (int g = 0; g < 4; ++g)
        xgw[g] = __hip_atomic_load(Xgu + xrow + g * 256, __ATOMIC_RELAXED,
                                   __HIP_MEMORY_SCOPE_AGENT);
    }

    // ---- h_t @ W_h slice: wave = gate, full K=512, 2 n-tiles ----
    const unsigned short* hrow =
        hbuf + ((size_t)(t & 1) * 64 * 512) + (size_t)gb * 16 * 512;
    f32x4 acc0 = {0.f, 0.f, 0.f, 0.f}, acc1 = {0.f, 0.f, 0.f, 0.f};
#pragma unroll
    for (int kk = 0; kk < 512; kk += 32) {
      int k = kk + quad * 8;
      const unsigned long long* ap =
          (const unsigned long long*)(hrow + (size_t)m * 512 + k);
      union { short8 v; unsigned long long qq[2]; } au;
      au.qq[0] = __hip_atomic_load(ap, __ATOMIC_RELAXED, __HIP_MEMORY_SCOPE_AGENT);
      au.qq[1] = __hip_atomic_load(ap + 1, __ATOMIC_RELAXED, __HIP_MEMORY_SCOPE_AGENT);
      short8 bv0 = *(const short8*)(wl0 + k);
      short8 bv1 = *(const short8*)(wl1 + k);
      acc0 = __builtin_amdgcn_mfma_f32_16x16x32_bf16(au.v, bv0, acc0, 0, 0, 0);
      acc1 = __builtin_amdgcn_mfma_f32_16x16x32_bf16(au.v, bv1, acc1, 0, 0, 0);
    }
#pragma unroll
    for (int r = 0; r < 4; ++r) {
      sm.r.Cg[wave][quad * 4 + r][m] = acc0[r];
      sm.r.Cg[wave][quad * 4 + r][16 + m] = acc1[r];
    }
    __syncthreads();

    // ---- gates: each thread owns (bb, jj2) and (bb, jj2+1) ----
    float gf0 = sm.r.Cg[0][bb][jj2]     + bfv.x + bf2f(xgw[0] & 0xffff);
    float gf1 = sm.r.Cg[0][bb][jj2 + 1] + bfv.y + bf2f(xgw[0] >> 16);
    float gi0 = sm.r.Cg[1][bb][jj2]     + biv.x + bf2f(xgw[1] & 0xffff);
    float gi1 = sm.r.Cg[1][bb][jj2 + 1] + biv.y + bf2f(xgw[1] >> 16);
    float go0 = sm.r.Cg[2][bb][jj2]     + bov.x + bf2f(xgw[2] & 0xffff);
    float go1 = sm.r.Cg[2][bb][jj2 + 1] + bov.y + bf2f(xgw[2] >> 16);
    float gc0 = sm.r.Cg[3][bb][jj2]     + bcv.x + bf2f(xgw[3] & 0xffff);
    float gc1 = sm.r.Cg[3][bb][jj2 + 1] + bcv.y + bf2f(xgw[3] >> 16);

    float f0 = 1.f / (1.f + __expf(-gf0)), f1 = 1.f / (1.f + __expf(-gf1));
    float i0 = 1.f / (1.f + __expf(-gi0)), i1 = 1.f / (1.f + __expf(-gi1));
    float o0 = 1.f / (1.f + __expf(-go0)), o1 = 1.f / (1.f + __expf(-go1));
    float ch0 = 1.f - 2.f / (1.f + __expf(2.f * gc0));
    float ch1 = 1.f - 2.f / (1.f + __expf(2.f * gc1));
    c0 = f0 * c0 + i0 * ch0;
    c1 = f1 * c1 + i1 * ch1;
    float h0 = o0 * (1.f - 2.f / (1.f + __expf(2.f * c0)));
    float h1 = o1 * (1.f - 2.f / (1.f + __expf(2.f * c1)));

    float* orow = out + ((size_t)t * 64 + gb * 16 + bb) * 512 + gh * 32 + jj2;
    *(float2*)orow = make_float2(h0, h1);

    unsigned hp = (unsigned)f2bf(h0) | ((unsigned)f2bf(h1) << 16);
    __hip_atomic_store(
        (unsigned*)hbuf + (size_t)((t + 1) & 1) * 16384 +
            (gb * 16 + bb) * 256 + gh * 16 + rem,
        hp, __ATOMIC_RELAXED, __HIP_MEMORY_SCOPE_AGENT);

    if (t == T_STEPS - 1) {
      size_t base = (size_t)T_STEPS * 64 * 512;
      size_t off = (size_t)(gb * 16 + bb) * 512 + gh * 32 + jj2;
      *(float2*)(out + base + off) = make_float2(h0, h1);
      *(float2*)(out + base + 64 * 512 + off) = make_float2(c0, c1);
    }

    __syncthreads();  // drains all waves' vmcnt -> h stores landed in L3
    __builtin_amdgcn_fence(__ATOMIC_RELEASE, "workgroup");
    if (tid == 0)
      __hip_atomic_store(flags + myflag, t + 1, __ATOMIC_RELAXED,
                         __HIP_MEMORY_SCOPE_AGENT);
  }
}

// ------------------------------- launch ------------------------------------

extern "C" void kernel_launch(void* const* d_in, const int* in_sizes, int n_in,
                              void* d_out, int out_size, void* d_ws, size_t ws_size,
                              hipStream_t stream) {
  const float* X    = (const float*)d_in[0];
  const float* W_xf = (const float*)d_in[1];
  const float* W_hf = (const float*)d_in[2];
  const float* b_f  = (const float*)d_in[3];
  const float* W_xi = (const float*)d_in[4];
  const float* W_hi = (const float*)d_in[5];
  const float* b_i  = (const float*)d_in[6];
  const float* W_xo = (const float*)d_in[7];
  const float* W_ho = (const float*)d_in[8];
  const float* b_o  = (const float*)d_in[9];
  const float* W_xc = (const float*)d_in[10];
  const float* W_hc = (const float*)d_in[11];
  const float* b_c  = (const float*)d_in[12];
  float* out = (float*)d_out;

  char* ws = (char*)d_ws;
  unsigned short* Xb   = (unsigned short*)(ws + 0LL);           // 134,217,728 B
  unsigned short* Xg   = (unsigned short*)(ws + 134217728LL);   // 536,870,912 B
  unsigned short* Wxt  = (unsigned short*)(ws + 671088640LL);   //   2,097,152 B
  unsigned short* Wht  = (unsigned short*)(ws + 673185792LL);   //   2,097,152 B
  unsigned short* hbuf = (unsigned short*)(ws + 675282944LL);   //     131,072 B
  int* flags           = (int*)(ws + 675414016LL);              //       4,096 B
  int* xgprog          = (int*)(ws + 675418112LL);              //       4,096 B

  cast_x_kernel<<<dim3(32768), dim3(256), 0, stream>>>(X, Xb);
  pack_w_kernel<<<dim3(2048), dim3(256), 0, stream>>>(W_xf, W_xi, W_xo, W_xc, Wxt);
  pack_w_kernel<<<dim3(2048), dim3(256), 0, stream>>>(W_hf, W_hi, W_ho, W_hc, Wht);
  init_kernel<<<dim3(256), dim3(256), 0, stream>>>(hbuf, flags, xgprog);
  lstm_fused_kernel<<<dim3(256), dim3(256), 0, stream>>>(
      Xb, Wxt, Wht, Xg, b_f, b_i, b_o, b_c, out, hbuf, flags, xgprog);
}